// Round 10
// baseline (223.126 us; speedup 1.0000x reference)
//
#include <hip/hip_runtime.h>
#include <stdint.h>

// ChamferDistance2D: B=8, N=M=8192, fp32, scalar out.
// R10: R9's exact grid-NN (validated green) with the serial-tail fixed.
// R9 counters: query_k 94.5us @ VALUBusy 4.3% -> duration = worst lane's
// serial dependent-load chain (tail queries at r>3.5 need rings ~15-38).
// Split: query1 = rings 0-1 (3x3) for ALL queries, uniform; ~94% finish
// (best <= h^2). Leftovers -> worklist (wave-aggregated push). query2 = ONE
// WAVE per leftover query: lanes scan ring cells in parallel, rings in
// geometric bands (4,8,16,32); exact stop: best <= (c1*h)^2 after completing
// ring c1 (projection is 1-Lipschitz -> unscanned points >= c1*h away).
// ws: counts 1MB @0, start 1MB @1M, cursor 1MB @2M, sorted 1MB @3M,
//     bestbuf 512KB @4M, wl 512KB @4.5M, wl_count 4B @5M.

#define BATCH 8
#define NPTS  8192
#define TPB   256
#define GRID  128
#define G2    (GRID * GRID)
#define BOX   4.25f
#define H     0.06640625f        // 8.5/128, exact in binary
#define NSB   (2 * BATCH)

__device__ inline int cellof(float v) {
    int c = (int)((v + BOX) * (1.0f / H));
    return min(max(c, 0), GRID - 1);
}

// grid = 512. Also zeroes out & wl_count (runs before the query kernels in-stream).
__global__ void hist_k(const float2* __restrict__ p1, const float2* __restrict__ p2,
                       int* __restrict__ counts, float* __restrict__ out,
                       int* __restrict__ wl_count) {
    int g = blockIdx.x * TPB + threadIdx.x;
    if (g == 0) { *out = 0.0f; *wl_count = 0; }
    int side = g >> 16, b = (g >> 13) & 7, i = g & (NPTS - 1);
    float2 P = (side ? p2 : p1)[(size_t)b * NPTS + i];
    int cell = cellof(P.y) * GRID + cellof(P.x);
    atomicAdd(&counts[(side * BATCH + b) * G2 + cell], 1);
}

// grid = 16; block sb scans its 16384-cell grid -> start (excl), cursor copy
__global__ __launch_bounds__(TPB) void prefix_k(const int* __restrict__ counts,
                                                int* __restrict__ start,
                                                int* __restrict__ cursor) {
    __shared__ int psum[TPB];
    const int CPT = G2 / TPB;
    int base = blockIdx.x * G2;
    int t = threadIdx.x;
    int s = 0;
    for (int u = 0; u < CPT; ++u) s += counts[base + t * CPT + u];
    psum[t] = s;
    __syncthreads();
    for (int off = 1; off < TPB; off <<= 1) {
        int v = (t >= off) ? psum[t - off] : 0;
        __syncthreads();
        psum[t] += v;
        __syncthreads();
    }
    int run = psum[t] - s;
    for (int u = 0; u < CPT; ++u) {
        int idx = base + t * CPT + u;
        int c = counts[idx];
        start[idx] = run;
        cursor[idx] = run;
        run += c;
    }
}

// grid = 512
__global__ void scatter_k(const float2* __restrict__ p1, const float2* __restrict__ p2,
                          int* __restrict__ cursor, float2* __restrict__ sorted) {
    int g = blockIdx.x * TPB + threadIdx.x;
    int side = g >> 16, b = (g >> 13) & 7, i = g & (NPTS - 1);
    float2 P = (side ? p2 : p1)[(size_t)b * NPTS + i];
    int cell = cellof(P.y) * GRID + cellof(P.x);
    int sb = side * BATCH + b;
    int pos = atomicAdd(&cursor[sb * G2 + cell], 1);
    sorted[(size_t)sb * NPTS + pos] = P;
}

// grid = 512. Rings 0-1 for every query; finished -> block sum; else worklist.
__global__ __launch_bounds__(TPB) void query1_k(const float2* __restrict__ sorted,
                                                const int* __restrict__ start,
                                                const int* __restrict__ counts,
                                                float* __restrict__ bestbuf,
                                                int* __restrict__ wl,
                                                int* __restrict__ wl_count,
                                                float* __restrict__ out) {
    int g = blockIdx.x * TPB + threadIdx.x;
    int sb = g >> 13;
    float2 q = sorted[g];                      // queries in sorted order
    int tg = sb ^ 8;                           // opposite side, same batch
    const float2* __restrict__ pts = sorted + (size_t)tg * NPTS;
    const int* __restrict__ st = start + tg * G2;
    const int* __restrict__ ct = counts + tg * G2;

    int cx = cellof(q.x), cy = cellof(q.y);
    int xlo = max(cx - 1, 0), xhi = min(cx + 1, GRID - 1);
    float best = 3.0e38f;
#pragma unroll
    for (int dy = -1; dy <= 1; ++dy) {
        int y = cy + dy;
        if (y < 0 || y > GRID - 1) continue;
        int s = st[y * GRID + xlo];
        int e = st[y * GRID + xhi] + ct[y * GRID + xhi];
        for (int k = s; k < e; ++k) {
            float2 p = pts[k];
            float dx = q.x - p.x, dyv = q.y - p.y;
            best = fminf(best, fmaf(dx, dx, dyv * dyv));
        }
    }
    bool done = best <= H * H;                 // unscanned cells are ring>=2 -> >= h away

    // wave-aggregated worklist push
    int lane = threadIdx.x & 63;
    unsigned long long mask = __ballot(!done);
    int base = 0;
    if (lane == 0 && mask) base = atomicAdd(wl_count, __popcll(mask));
    base = __shfl(base, 0, 64);
    if (!done) {
        int off = __popcll(mask & ((1ull << lane) - 1ull));
        wl[base + off] = g;
        bestbuf[g] = best;
    }

    // block-sum finished contributions
    float d = done ? best : 0.0f;
#pragma unroll
    for (int off = 32; off > 0; off >>= 1)
        d += __shfl_down(d, off, 64);
    __shared__ float wsum[TPB / 64];
    int w = threadIdx.x >> 6;
    if (lane == 0) wsum[w] = d;
    __syncthreads();
    if (threadIdx.x == 0)
        atomicAdd(out, (wsum[0] + wsum[1] + wsum[2] + wsum[3]) * (1.0f / NPTS));
}

// grid = 2048 blocks -> 8192 waves; one wave per leftover query (grid-stride).
__global__ __launch_bounds__(TPB) void query2_k(const float2* __restrict__ sorted,
                                                const int* __restrict__ start,
                                                const int* __restrict__ counts,
                                                const float* __restrict__ bestbuf,
                                                const int* __restrict__ wl,
                                                const int* __restrict__ wl_count,
                                                float* __restrict__ out) {
    int lane = threadIdx.x & 63;
    int wv = (blockIdx.x * TPB + threadIdx.x) >> 6;
    int nwaves = (gridDim.x * TPB) >> 6;
    int nwl = *wl_count;

    for (int widx = wv; widx < nwl; widx += nwaves) {
        int g = wl[widx];
        float2 q = sorted[g];
        int tg = (g >> 13) ^ 8;
        const float2* __restrict__ pts = sorted + (size_t)tg * NPTS;
        const int* __restrict__ st = start + tg * G2;
        const int* __restrict__ ct = counts + tg * G2;

        int cx = cellof(q.x), cy = cellof(q.y);
        int cmax = max(max(cx, GRID - 1 - cx), max(cy, GRID - 1 - cy));
        float best = bestbuf[g];

        int c0 = 2, bw = 4;
        while (c0 <= cmax) {
            int c1 = min(c0 + bw - 1, cmax);
            float lb = best;
            for (int c = c0; c <= c1; ++c) {       // rings in band; lanes split cells
                int ncell = 8 * c;
                for (int idx = lane; idx < ncell; idx += 64) {
                    int x, y;
                    if (idx < 2 * c + 1)          { x = cx - c + idx;                 y = cy - c; }
                    else if (idx < 4 * c + 2)     { x = cx - c + (idx - (2 * c + 1)); y = cy + c; }
                    else { int rem = idx - (4 * c + 2); y = cy - c + 1 + (rem >> 1);
                           x = (rem & 1) ? cx + c : cx - c; }
                    if (x < 0 || x > GRID - 1 || y < 0 || y > GRID - 1) continue;
                    int cell = y * GRID + x;
                    int s = st[cell];
                    int e = s + ct[cell];
                    for (int k = s; k < e; ++k) {
                        float2 p = pts[k];
                        float dx = q.x - p.x, dy = q.y - p.y;
                        lb = fminf(lb, fmaf(dx, dx, dy * dy));
                    }
                }
            }
#pragma unroll
            for (int off = 1; off < 64; off <<= 1)
                lb = fminf(lb, __shfl_xor(lb, off, 64));
            best = lb;
            float bd = (float)c1 * H;
            if (best <= bd * bd) break;            // exact: unscanned >= c1*h
            c0 = c1 + 1;
            bw = min(bw * 2, 32);
        }
        if (lane == 0) atomicAdd(out, best * (1.0f / NPTS));
    }
}

extern "C" void kernel_launch(void* const* d_in, const int* in_sizes, int n_in,
                              void* d_out, int out_size, void* d_ws, size_t ws_size,
                              hipStream_t stream) {
    const float2* p1 = (const float2*)d_in[0];
    const float2* p2 = (const float2*)d_in[1];
    float* out = (float*)d_out;

    char* ws = (char*)d_ws;
    int*    counts  = (int*)(ws);
    int*    start   = (int*)(ws + (size_t)1 * 1024 * 1024);
    int*    cursor  = (int*)(ws + (size_t)2 * 1024 * 1024);
    float2* sorted  = (float2*)(ws + (size_t)3 * 1024 * 1024);
    float*  bestbuf = (float*)(ws + (size_t)4 * 1024 * 1024);
    int*    wl      = (int*)(ws + (size_t)4608 * 1024);
    int*    wl_cnt  = (int*)(ws + (size_t)5 * 1024 * 1024);
    // ~5 MB total (>=20 MB proven available)

    hipMemsetAsync(counts, 0, (size_t)NSB * G2 * sizeof(int), stream);

    const int NQB = 2 * BATCH * NPTS / TPB;   // 512
    hist_k<<<NQB, TPB, 0, stream>>>(p1, p2, counts, out, wl_cnt);
    prefix_k<<<NSB, TPB, 0, stream>>>(counts, start, cursor);
    scatter_k<<<NQB, TPB, 0, stream>>>(p1, p2, cursor, sorted);
    query1_k<<<NQB, TPB, 0, stream>>>(sorted, start, counts, bestbuf, wl, wl_cnt, out);
    query2_k<<<2048, TPB, 0, stream>>>(sorted, start, counts, bestbuf, wl, wl_cnt, out);
}

// Round 11
// 201.495 us; speedup vs baseline: 1.1074x; 1.1074x over previous
//
#include <hip/hip_runtime.h>
#include <stdint.h>

// ChamferDistance2D: B=8, N=M=8192, fp32, scalar out.
// R11: exact grid-NN (R9/R10 validated) with the tail made THROUGHPUT-bound.
// R10 counters: ring-walking tail waves serialize on dependent cell-metadata
// loads (~900cyc each, m126) -> 130us at 3.6% VALUBusy. Fix: leftover queries
// (~5%, best > h^2 after the 3x3 pass) are brute-forced against ALL 8192
// opposite-side points — 5.7e7 pairs total (~0.05% of the O(N^2) workload),
// coalesced float2 streams from L2 (437 MB @ ~34 TB/s ~ 13us), zero
// divergence, trivially exact.
// Pipeline: memset counts -> hist -> prefix -> scatter(counting sort) ->
// query1 (rings 0-1, done iff best<=h^2; worklist push wave-aggregated) ->
// query2 (one wave per leftover, full scan).
// ws: counts 1MB @0, start 1MB @1M, cursor 1MB @2M, sorted 1MB @3M,
//     wl 512KB @4M, wl_count 4B @4.5M.

#define BATCH 8
#define NPTS  8192
#define TPB   256
#define GRID  128
#define G2    (GRID * GRID)
#define BOX   4.25f
#define H     0.06640625f        // 8.5/128, exact in binary
#define NSB   (2 * BATCH)

__device__ inline float min3f(float a, float b, float c) {
    float d;
    asm("v_min3_f32 %0, %1, %2, %3" : "=v"(d) : "v"(a), "v"(b), "v"(c));
    return d;
}

__device__ inline int cellof(float v) {
    int c = (int)((v + BOX) * (1.0f / H));
    return min(max(c, 0), GRID - 1);
}

// grid = 512. Also zeroes out & wl_count (stream-ordered before the queries).
__global__ void hist_k(const float2* __restrict__ p1, const float2* __restrict__ p2,
                       int* __restrict__ counts, float* __restrict__ out,
                       int* __restrict__ wl_count) {
    int g = blockIdx.x * TPB + threadIdx.x;
    if (g == 0) { *out = 0.0f; *wl_count = 0; }
    int side = g >> 16, b = (g >> 13) & 7, i = g & (NPTS - 1);
    float2 P = (side ? p2 : p1)[(size_t)b * NPTS + i];
    int cell = cellof(P.y) * GRID + cellof(P.x);
    atomicAdd(&counts[(side * BATCH + b) * G2 + cell], 1);
}

// grid = 16; block sb scans its 16384-cell grid -> start (excl), cursor copy
__global__ __launch_bounds__(TPB) void prefix_k(const int* __restrict__ counts,
                                                int* __restrict__ start,
                                                int* __restrict__ cursor) {
    __shared__ int psum[TPB];
    const int CPT = G2 / TPB;
    int base = blockIdx.x * G2;
    int t = threadIdx.x;
    int s = 0;
    for (int u = 0; u < CPT; ++u) s += counts[base + t * CPT + u];
    psum[t] = s;
    __syncthreads();
    for (int off = 1; off < TPB; off <<= 1) {
        int v = (t >= off) ? psum[t - off] : 0;
        __syncthreads();
        psum[t] += v;
        __syncthreads();
    }
    int run = psum[t] - s;
    for (int u = 0; u < CPT; ++u) {
        int idx = base + t * CPT + u;
        int c = counts[idx];
        start[idx] = run;
        cursor[idx] = run;
        run += c;
    }
}

// grid = 512
__global__ void scatter_k(const float2* __restrict__ p1, const float2* __restrict__ p2,
                          int* __restrict__ cursor, float2* __restrict__ sorted) {
    int g = blockIdx.x * TPB + threadIdx.x;
    int side = g >> 16, b = (g >> 13) & 7, i = g & (NPTS - 1);
    float2 P = (side ? p2 : p1)[(size_t)b * NPTS + i];
    int cell = cellof(P.y) * GRID + cellof(P.x);
    int sb = side * BATCH + b;
    int pos = atomicAdd(&cursor[sb * G2 + cell], 1);
    sorted[(size_t)sb * NPTS + pos] = P;
}

// grid = 512. Rings 0-1 for every query; finished -> block sum; else worklist.
__global__ __launch_bounds__(TPB) void query1_k(const float2* __restrict__ sorted,
                                                const int* __restrict__ start,
                                                const int* __restrict__ counts,
                                                int* __restrict__ wl,
                                                int* __restrict__ wl_count,
                                                float* __restrict__ out) {
    int g = blockIdx.x * TPB + threadIdx.x;
    int sb = g >> 13;
    float2 q = sorted[g];                      // queries in sorted order
    int tg = sb ^ 8;                           // opposite side, same batch
    const float2* __restrict__ pts = sorted + (size_t)tg * NPTS;
    const int* __restrict__ st = start + tg * G2;
    const int* __restrict__ ct = counts + tg * G2;

    int cx = cellof(q.x), cy = cellof(q.y);
    int xlo = max(cx - 1, 0), xhi = min(cx + 1, GRID - 1);
    float best = 3.0e38f;
#pragma unroll
    for (int dy = -1; dy <= 1; ++dy) {
        int y = cy + dy;
        if (y < 0 || y > GRID - 1) continue;
        int s = st[y * GRID + xlo];
        int e = st[y * GRID + xhi] + ct[y * GRID + xhi];
        for (int k = s; k < e; ++k) {
            float2 p = pts[k];
            float dx = q.x - p.x, dyv = q.y - p.y;
            best = fminf(best, fmaf(dx, dx, dyv * dyv));
        }
    }
    bool done = best <= H * H;                 // unscanned cells (ring>=2) are >= h away

    // wave-aggregated worklist push
    int lane = threadIdx.x & 63;
    unsigned long long mask = __ballot(!done);
    int base = 0;
    if (lane == 0 && mask) base = atomicAdd(wl_count, __popcll(mask));
    base = __shfl(base, 0, 64);
    if (!done) {
        int off = __popcll(mask & ((1ull << lane) - 1ull));
        wl[base + off] = g;
    }

    // block-sum finished contributions
    float d = done ? best : 0.0f;
#pragma unroll
    for (int off = 32; off > 0; off >>= 1)
        d += __shfl_down(d, off, 64);
    __shared__ float wsum[TPB / 64];
    int w = threadIdx.x >> 6;
    if (lane == 0) wsum[w] = d;
    __syncthreads();
    if (threadIdx.x == 0)
        atomicAdd(out, (wsum[0] + wsum[1] + wsum[2] + wsum[3]) * (1.0f / NPTS));
}

// grid = 2048 blocks = 8192 waves; ONE WAVE per leftover query, full 8192-point
// scan (coalesced, L2-resident, exact by construction).
__global__ __launch_bounds__(TPB) void query2_k(const float2* __restrict__ sorted,
                                                const int* __restrict__ wl,
                                                const int* __restrict__ wl_count,
                                                float* __restrict__ out) {
    int lane = threadIdx.x & 63;
    int wv = (blockIdx.x * TPB + threadIdx.x) >> 6;
    int nwaves = (gridDim.x * TPB) >> 6;
    int nwl = *wl_count;

    for (int widx = wv; widx < nwl; widx += nwaves) {
        int g = wl[widx];
        float2 q = sorted[g];
        const float2* __restrict__ pts = sorted + ((size_t)((g >> 13) ^ 8)) * NPTS;

        float best = 3.0e38f;
        for (int k0 = 0; k0 < NPTS; k0 += 256) {       // 128 pts/lane, unroll 4
            float2 p0 = pts[k0 + lane];
            float2 p1 = pts[k0 + 64 + lane];
            float2 p2 = pts[k0 + 128 + lane];
            float2 p3 = pts[k0 + 192 + lane];
            float dx0 = q.x - p0.x, dy0 = q.y - p0.y;
            float dx1 = q.x - p1.x, dy1 = q.y - p1.y;
            float dx2 = q.x - p2.x, dy2 = q.y - p2.y;
            float dx3 = q.x - p3.x, dy3 = q.y - p3.y;
            float d0 = fmaf(dx0, dx0, dy0 * dy0);
            float d1 = fmaf(dx1, dx1, dy1 * dy1);
            float d2 = fmaf(dx2, dx2, dy2 * dy2);
            float d3 = fmaf(dx3, dx3, dy3 * dy3);
            best = min3f(best, d0, d1);
            best = min3f(best, d2, d3);
        }
#pragma unroll
        for (int off = 1; off < 64; off <<= 1)
            best = fminf(best, __shfl_xor(best, off, 64));
        if (lane == 0) atomicAdd(out, best * (1.0f / NPTS));
    }
}

extern "C" void kernel_launch(void* const* d_in, const int* in_sizes, int n_in,
                              void* d_out, int out_size, void* d_ws, size_t ws_size,
                              hipStream_t stream) {
    const float2* p1 = (const float2*)d_in[0];
    const float2* p2 = (const float2*)d_in[1];
    float* out = (float*)d_out;

    char* ws = (char*)d_ws;
    int*    counts = (int*)(ws);
    int*    start  = (int*)(ws + (size_t)1 * 1024 * 1024);
    int*    cursor = (int*)(ws + (size_t)2 * 1024 * 1024);
    float2* sorted = (float2*)(ws + (size_t)3 * 1024 * 1024);
    int*    wl     = (int*)(ws + (size_t)4 * 1024 * 1024);
    int*    wl_cnt = (int*)(ws + (size_t)4608 * 1024);
    // ~4.5 MB total (>=20 MB proven available)

    hipMemsetAsync(counts, 0, (size_t)NSB * G2 * sizeof(int), stream);

    const int NQB = 2 * BATCH * NPTS / TPB;   // 512
    hist_k<<<NQB, TPB, 0, stream>>>(p1, p2, counts, out, wl_cnt);
    prefix_k<<<NSB, TPB, 0, stream>>>(counts, start, cursor);
    scatter_k<<<NQB, TPB, 0, stream>>>(p1, p2, cursor, sorted);
    query1_k<<<NQB, TPB, 0, stream>>>(sorted, start, counts, wl, wl_cnt, out);
    query2_k<<<2048, TPB, 0, stream>>>(sorted, wl, wl_cnt, out);
}

// Round 12
// 133.357 us; speedup vs baseline: 1.6731x; 1.5109x over previous
//
#include <hip/hip_runtime.h>
#include <stdint.h>

// ChamferDistance2D: B=8, N=M=8192, fp32, scalar out.
// R12 = R11 (green) with ONE mechanism changed: no same-address atomics.
// R11 counters: query2_k 101us @ VALUBusy 7.2%, FETCH 4MB — the ~6.5K
// device-scope atomicAdds to the single `out` address serialize at ~15ns
// each (~98us) at the owning L2 bank. Fix: per-block partial sums to a
// buffer (plain stores), tiny finalize kernel reduces 2560 floats -> out.
// Pipeline: memset counts -> hist -> prefix -> scatter -> query1 (rings 0-1,
// ~95% finish; leftovers to worklist) -> query2 (one wave per leftover,
// full 8192-pt coalesced L2 scan, exact) -> finalize.
// ws: counts 1MB @0, start 1MB @1M, cursor 1MB @2M, sorted 1MB @3M,
//     wl 512KB @4M, wl_count 4B @4.5M, partial 10KB @5M.

#define BATCH 8
#define NPTS  8192
#define TPB   256
#define GRID  128
#define G2    (GRID * GRID)
#define BOX   4.25f
#define H     0.06640625f        // 8.5/128, exact in binary
#define NSB   (2 * BATCH)
#define NQB   512                // query1/hist/scatter blocks
#define NQ2B  2048               // query2 blocks
#define NPART (NQB + NQ2B)       // 2560 partial slots

__device__ inline float min3f(float a, float b, float c) {
    float d;
    asm("v_min3_f32 %0, %1, %2, %3" : "=v"(d) : "v"(a), "v"(b), "v"(c));
    return d;
}

__device__ inline int cellof(float v) {
    int c = (int)((v + BOX) * (1.0f / H));
    return min(max(c, 0), GRID - 1);
}

// grid = 512. Also zeroes wl_count (stream-ordered before query1).
__global__ void hist_k(const float2* __restrict__ p1, const float2* __restrict__ p2,
                       int* __restrict__ counts, int* __restrict__ wl_count) {
    int g = blockIdx.x * TPB + threadIdx.x;
    if (g == 0) *wl_count = 0;
    int side = g >> 16, b = (g >> 13) & 7, i = g & (NPTS - 1);
    float2 P = (side ? p2 : p1)[(size_t)b * NPTS + i];
    int cell = cellof(P.y) * GRID + cellof(P.x);
    atomicAdd(&counts[(side * BATCH + b) * G2 + cell], 1);
}

// grid = 16; block sb scans its 16384-cell grid -> start (excl), cursor copy
__global__ __launch_bounds__(TPB) void prefix_k(const int* __restrict__ counts,
                                                int* __restrict__ start,
                                                int* __restrict__ cursor) {
    __shared__ int psum[TPB];
    const int CPT = G2 / TPB;
    int base = blockIdx.x * G2;
    int t = threadIdx.x;
    int s = 0;
    for (int u = 0; u < CPT; ++u) s += counts[base + t * CPT + u];
    psum[t] = s;
    __syncthreads();
    for (int off = 1; off < TPB; off <<= 1) {
        int v = (t >= off) ? psum[t - off] : 0;
        __syncthreads();
        psum[t] += v;
        __syncthreads();
    }
    int run = psum[t] - s;
    for (int u = 0; u < CPT; ++u) {
        int idx = base + t * CPT + u;
        int c = counts[idx];
        start[idx] = run;
        cursor[idx] = run;
        run += c;
    }
}

// grid = 512
__global__ void scatter_k(const float2* __restrict__ p1, const float2* __restrict__ p2,
                          int* __restrict__ cursor, float2* __restrict__ sorted) {
    int g = blockIdx.x * TPB + threadIdx.x;
    int side = g >> 16, b = (g >> 13) & 7, i = g & (NPTS - 1);
    float2 P = (side ? p2 : p1)[(size_t)b * NPTS + i];
    int cell = cellof(P.y) * GRID + cellof(P.x);
    int sb = side * BATCH + b;
    int pos = atomicAdd(&cursor[sb * G2 + cell], 1);
    sorted[(size_t)sb * NPTS + pos] = P;
}

// grid = 512. Rings 0-1 for every query; block sum -> partial[blockIdx].
__global__ __launch_bounds__(TPB) void query1_k(const float2* __restrict__ sorted,
                                                const int* __restrict__ start,
                                                const int* __restrict__ counts,
                                                int* __restrict__ wl,
                                                int* __restrict__ wl_count,
                                                float* __restrict__ partial) {
    int g = blockIdx.x * TPB + threadIdx.x;
    int sb = g >> 13;
    float2 q = sorted[g];                      // queries in sorted order
    int tg = sb ^ 8;                           // opposite side, same batch
    const float2* __restrict__ pts = sorted + (size_t)tg * NPTS;
    const int* __restrict__ st = start + tg * G2;
    const int* __restrict__ ct = counts + tg * G2;

    int cx = cellof(q.x), cy = cellof(q.y);
    int xlo = max(cx - 1, 0), xhi = min(cx + 1, GRID - 1);
    float best = 3.0e38f;
#pragma unroll
    for (int dy = -1; dy <= 1; ++dy) {
        int y = cy + dy;
        if (y < 0 || y > GRID - 1) continue;
        int s = st[y * GRID + xlo];
        int e = st[y * GRID + xhi] + ct[y * GRID + xhi];
        for (int k = s; k < e; ++k) {
            float2 p = pts[k];
            float dx = q.x - p.x, dyv = q.y - p.y;
            best = fminf(best, fmaf(dx, dx, dyv * dyv));
        }
    }
    bool done = best <= H * H;                 // unscanned cells (ring>=2) are >= h away

    // wave-aggregated worklist push
    int lane = threadIdx.x & 63;
    unsigned long long mask = __ballot(!done);
    int base = 0;
    if (lane == 0 && mask) base = atomicAdd(wl_count, __popcll(mask));
    base = __shfl(base, 0, 64);
    if (!done) {
        int off = __popcll(mask & ((1ull << lane) - 1ull));
        wl[base + off] = g;
    }

    // block-sum finished contributions -> partial (no atomics)
    float d = done ? best : 0.0f;
#pragma unroll
    for (int off = 32; off > 0; off >>= 1)
        d += __shfl_down(d, off, 64);
    __shared__ float wsum[TPB / 64];
    int w = threadIdx.x >> 6;
    if (lane == 0) wsum[w] = d;
    __syncthreads();
    if (threadIdx.x == 0)
        partial[blockIdx.x] = wsum[0] + wsum[1] + wsum[2] + wsum[3];
}

// grid = 2048 blocks = 8192 waves; ONE WAVE per leftover query, full 8192-pt
// coalesced scan. Block accumulates -> partial[512 + blockIdx] (no atomics).
__global__ __launch_bounds__(TPB) void query2_k(const float2* __restrict__ sorted,
                                                const int* __restrict__ wl,
                                                const int* __restrict__ wl_count,
                                                float* __restrict__ partial) {
    int lane = threadIdx.x & 63;
    int wv = (blockIdx.x * TPB + threadIdx.x) >> 6;
    int nwaves = (gridDim.x * TPB) >> 6;
    int nwl = *wl_count;

    float acc = 0.0f;
    for (int widx = wv; widx < nwl; widx += nwaves) {
        int g = wl[widx];
        float2 q = sorted[g];
        const float2* __restrict__ pts = sorted + ((size_t)((g >> 13) ^ 8)) * NPTS;

        float best = 3.0e38f;
        for (int k0 = 0; k0 < NPTS; k0 += 256) {       // 128 pts/lane, unroll 4
            float2 p0 = pts[k0 + lane];
            float2 p1 = pts[k0 + 64 + lane];
            float2 p2 = pts[k0 + 128 + lane];
            float2 p3 = pts[k0 + 192 + lane];
            float dx0 = q.x - p0.x, dy0 = q.y - p0.y;
            float dx1 = q.x - p1.x, dy1 = q.y - p1.y;
            float dx2 = q.x - p2.x, dy2 = q.y - p2.y;
            float dx3 = q.x - p3.x, dy3 = q.y - p3.y;
            float d0 = fmaf(dx0, dx0, dy0 * dy0);
            float d1 = fmaf(dx1, dx1, dy1 * dy1);
            float d2 = fmaf(dx2, dx2, dy2 * dy2);
            float d3 = fmaf(dx3, dx3, dy3 * dy3);
            best = min3f(best, d0, d1);
            best = min3f(best, d2, d3);
        }
#pragma unroll
        for (int off = 1; off < 64; off <<= 1)
            best = fminf(best, __shfl_xor(best, off, 64));
        if (lane == 0) acc += best;
    }

    __shared__ float wsum[TPB / 64];
    int w = threadIdx.x >> 6;
    if (lane == 0) wsum[w] = acc;
    __syncthreads();
    if (threadIdx.x == 0)
        partial[NQB + blockIdx.x] = wsum[0] + wsum[1] + wsum[2] + wsum[3];
}

// 1 block: sum 2560 partials -> out (single plain store, no atomics anywhere)
__global__ __launch_bounds__(TPB) void finalize_k(const float* __restrict__ partial,
                                                  float* __restrict__ out) {
    int t = threadIdx.x;
    float s = 0.0f;
    for (int i = t; i < NPART; i += TPB) s += partial[i];
#pragma unroll
    for (int off = 32; off > 0; off >>= 1)
        s += __shfl_down(s, off, 64);
    __shared__ float wsum[TPB / 64];
    int lane = t & 63, w = t >> 6;
    if (lane == 0) wsum[w] = s;
    __syncthreads();
    if (t == 0)
        *out = (wsum[0] + wsum[1] + wsum[2] + wsum[3]) * (1.0f / NPTS);
}

extern "C" void kernel_launch(void* const* d_in, const int* in_sizes, int n_in,
                              void* d_out, int out_size, void* d_ws, size_t ws_size,
                              hipStream_t stream) {
    const float2* p1 = (const float2*)d_in[0];
    const float2* p2 = (const float2*)d_in[1];
    float* out = (float*)d_out;

    char* ws = (char*)d_ws;
    int*    counts  = (int*)(ws);
    int*    start   = (int*)(ws + (size_t)1 * 1024 * 1024);
    int*    cursor  = (int*)(ws + (size_t)2 * 1024 * 1024);
    float2* sorted  = (float2*)(ws + (size_t)3 * 1024 * 1024);
    int*    wl      = (int*)(ws + (size_t)4 * 1024 * 1024);
    int*    wl_cnt  = (int*)(ws + (size_t)4608 * 1024);
    float*  partial = (float*)(ws + (size_t)5 * 1024 * 1024);
    // ~5 MB total (>=20 MB proven available)

    hipMemsetAsync(counts, 0, (size_t)NSB * G2 * sizeof(int), stream);

    hist_k<<<NQB, TPB, 0, stream>>>(p1, p2, counts, wl_cnt);
    prefix_k<<<NSB, TPB, 0, stream>>>(counts, start, cursor);
    scatter_k<<<NQB, TPB, 0, stream>>>(p1, p2, cursor, sorted);
    query1_k<<<NQB, TPB, 0, stream>>>(sorted, start, counts, wl, wl_cnt, partial);
    query2_k<<<NQ2B, TPB, 0, stream>>>(sorted, wl, wl_cnt, partial);
    finalize_k<<<1, TPB, 0, stream>>>(partial, out);
}